// Round 6
// baseline (3686.284 us; speedup 1.0000x reference)
//
#include <hip/hip_runtime.h>
#include <hip/hip_bf16.h>

// SimpleLSTM on MI355X — round 9: pipelined exchange loads, 1-barrier steps.
//   B=64, S=512, I=512, H=1024, gates = 4H = 4096
// R8 post-mortem: -6% only; VGPR stayed 128 (unified-file AGPRs absorb
// weights; spill theory mostly wrong). The real R8 regression source: the
// per-producer poll SERIALIZED 4 dependent far-memory round trips (~900cy
// each; FETCH excess ~200MB/step shows hex reloads come from HBM, not LLC).
// R9:
//   1. Preload ALL 4 chunks' tagged words (16 loads in flight), then
//      verify/extract/MFMA per chunk; reload ONLY failed chunks. Steady
//      state pays ONE ~900cy latency, not four.
//   2. One barrier/step: gtile double-buffered (LDS 128KB, still 1 block/CU);
//      publish issues right after gate math, no barrier in front of it.
//   3. x_{t+1} loads issued right AFTER the barrier (compiler drains
//      vmcnt(0) at barriers) -> hidden under elementwise; consumed after
//      publish.
//   Unchanged: agent-scope relaxed atomics, epoch-in-data tags, 8 groups x
//   32 CUs x 8 batches, wh/wx0 register-resident, launch_bounds(512,2).

#define BATCH 64
#define SEQ   512
#define ISZ   512
#define HSZ   1024
#define G4    4096

#define NGRP  8
#define GB    8      // batches per group
#define SLOTS 32     // CUs per group

typedef short bf16x8 __attribute__((ext_vector_type(8)));
typedef float f32x4  __attribute__((ext_vector_type(4)));

#define HEX_DW (NGRP * 2 * GB * HSZ)   // 131072 tagged dwords = 512 KB

static __device__ __forceinline__ short f2bf(float f) {
    __hip_bfloat16 h = __float2bfloat16(f);
    return *reinterpret_cast<short*>(&h);
}
static __device__ __forceinline__ float sigm(float x) {
    return 1.f / (1.f + __expf(-x));
}
static __device__ __forceinline__ float tanh_fast(float x) {
    x = fminf(15.f, fmaxf(-15.f, x));
    float e = __expf(2.f * x);
    return (e - 1.f) / (e + 1.f);
}

__global__ __launch_bounds__(512, 2) void lstm_persistent(
    const float* __restrict__ x,     // [B][S][I] fp32
    const float* __restrict__ W,     // [I+H][4H] fp32
    const float* __restrict__ bias,  // [4H] fp32
    float* __restrict__ out,         // [B][S][H], then [B][H] h, [B][H] c
    unsigned int* __restrict__ hx)   // [NGRP][2][GB][HSZ] tagged words
{
    const int tid  = threadIdx.x;
    const int bid  = blockIdx.x;
    const int g    = bid & 7;           // group
    const int s    = bid >> 3;          // slot 0..31: owns h-cols [32s, 32s+32)
    const int w    = tid >> 6;          // wave 0..7 = h-K slice [128w, +128)
    const int lane = tid & 63;
    const int m16  = lane & 15;
    const int quad = lane >> 4;

    __shared__ short wxl[8][8][64][8];        // Wx kk=1 frags, 64 KB
    __shared__ float gtile[2][8][8][8][16];   // double-buffered partials, 64 KB

    // ---- preload weights as MFMA B-fragments ----
    // slot s: 8 col-tiles ct -> col = (ct>>1)*1024 + s*32 + (ct&1)*16
    // B-frag (16x16x32): lane holds B[k = quad*8 + j][n = lane&15]
    bf16x8 wh[8][4];
    bf16x8 wx0[8];
    #pragma unroll
    for (int ct = 0; ct < 8; ++ct) {
        const int col = (ct >> 1) * 1024 + s * 32 + (ct & 1) * 16 + m16;
        #pragma unroll
        for (int kk = 0; kk < 4; ++kk)
            #pragma unroll
            for (int j = 0; j < 8; ++j)
                wh[ct][kk][j] = f2bf(W[(size_t)(ISZ + w * 128 + kk * 32 + quad * 8 + j) * G4 + col]);
        bf16x8 t0, t1;
        #pragma unroll
        for (int j = 0; j < 8; ++j) {
            t0[j] = f2bf(W[(size_t)(w * 64 + quad * 8 + j) * G4 + col]);
            t1[j] = f2bf(W[(size_t)(w * 64 + 32 + quad * 8 + j) * G4 + col]);
        }
        wx0[ct] = t0;
        *(bf16x8*)&wxl[w][ct][lane][0] = t1;
    }

    // elementwise mapping (tid < 256): eb = batch-in-group, ec = h-col-in-32
    const int eb = tid >> 5;
    const int ec = tid & 31;
    float bia[4] = {0.f, 0.f, 0.f, 0.f};
    if (tid < 256) {
        #pragma unroll
        for (int gg2 = 0; gg2 < 4; ++gg2) bia[gg2] = bias[gg2 * 1024 + s * 32 + ec];
    }
    float c_state = 0.f;

    unsigned int* hxg = hx + (size_t)g * (2 * GB * HSZ);

    f32x4 acc[8];
    f32x4 xr0 = {0,0,0,0}, xr1 = {0,0,0,0}, xr2 = {0,0,0,0}, xr3 = {0,0,0,0};

    // issue x loads for step tt (this wave's x-K slice [64w, +64))
    auto xload = [&](int tt) {
        if (m16 < 8) {
            const float* xr = x + ((size_t)(g * GB + m16) * SEQ + tt) * ISZ
                                + w * 64 + quad * 8;
            xr0 = *(const f32x4*)xr;
            xr1 = *(const f32x4*)(xr + 4);
            xr2 = *(const f32x4*)(xr + 32);
            xr3 = *(const f32x4*)(xr + 36);
        }
    };
    // acc = x_t @ Wx from the prefetched registers
    auto xmfma = [&]() {
        #pragma unroll
        for (int ct = 0; ct < 8; ++ct) acc[ct] = (f32x4){0.f, 0.f, 0.f, 0.f};
        bf16x8 a0, a1;
        a0[0]=f2bf(xr0[0]); a0[1]=f2bf(xr0[1]); a0[2]=f2bf(xr0[2]); a0[3]=f2bf(xr0[3]);
        a0[4]=f2bf(xr1[0]); a0[5]=f2bf(xr1[1]); a0[6]=f2bf(xr1[2]); a0[7]=f2bf(xr1[3]);
        a1[0]=f2bf(xr2[0]); a1[1]=f2bf(xr2[1]); a1[2]=f2bf(xr2[2]); a1[3]=f2bf(xr2[3]);
        a1[4]=f2bf(xr3[0]); a1[5]=f2bf(xr3[1]); a1[6]=f2bf(xr3[2]); a1[7]=f2bf(xr3[3]);
        #pragma unroll
        for (int ct = 0; ct < 8; ++ct)
            acc[ct] = __builtin_amdgcn_mfma_f32_16x16x32_bf16(a0, wx0[ct], acc[ct], 0, 0, 0);
        #pragma unroll
        for (int ct = 0; ct < 8; ++ct) {
            bf16x8 bx = *(const bf16x8*)&wxl[w][ct][lane][0];
            acc[ct] = __builtin_amdgcn_mfma_f32_16x16x32_bf16(a1, bx, acc[ct], 0, 0, 0);
        }
    };

    __syncthreads();   // wxl staged
    xload(0);
    xmfma();           // acc holds x-part of t=0

    for (int t = 0; t < SEQ; ++t) {
        // ---- poll + h-MFMA: preload ALL chunks, verify per chunk ----
        // tag target = t (t=0 passes immediately: memset zeros == epoch 0, h=0)
        const unsigned int tg = (unsigned int)t & 0xFFFFu;
        const int rb = (t + 1) & 1;
        const unsigned long long* hp64 = (const unsigned long long*)
            (hxg + ((size_t)rb * GB + m16) * HSZ + w * 128 + quad * 8);

        unsigned long long cbuf[4][4];
        #pragma unroll
        for (int kk = 0; kk < 4; ++kk)
            #pragma unroll
            for (int j = 0; j < 4; ++j) cbuf[kk][j] = 0ull;

        if (m16 < 8) {
            // all 16 loads issued together -> one far-memory latency
            #pragma unroll
            for (int kk = 0; kk < 4; ++kk)
                #pragma unroll
                for (int j = 0; j < 4; ++j)
                    cbuf[kk][j] = __hip_atomic_load(hp64 + kk * 16 + j,
                        __ATOMIC_RELAXED, __HIP_MEMORY_SCOPE_AGENT);
        }

        #pragma unroll
        for (int kk = 0; kk < 4; ++kk) {
            long long guard = 0;
            for (;;) {
                int ok = 1;
                if (m16 < 8) {
                    unsigned int bad = 0;
                    #pragma unroll
                    for (int j = 0; j < 4; ++j)
                        bad |= ((unsigned int)cbuf[kk][j] ^ tg)
                             | ((unsigned int)(cbuf[kk][j] >> 32) ^ tg);
                    ok = ((bad & 0xFFFFu) == 0u);
                }
                if (__all(ok)) break;
                __builtin_amdgcn_s_sleep(1);
                if (m16 < 8) {
                    #pragma unroll
                    for (int j = 0; j < 4; ++j)
                        cbuf[kk][j] = __hip_atomic_load(hp64 + kk * 16 + j,
                            __ATOMIC_RELAXED, __HIP_MEMORY_SCOPE_AGENT);
                }
                if (++guard > (1LL << 22)) break;   // safety valve (never trips)
            }
            bf16x8 ha;
            ha[0] = (short)((unsigned int)cbuf[kk][0] >> 16);
            ha[1] = (short)(cbuf[kk][0] >> 48);
            ha[2] = (short)((unsigned int)cbuf[kk][1] >> 16);
            ha[3] = (short)(cbuf[kk][1] >> 48);
            ha[4] = (short)((unsigned int)cbuf[kk][2] >> 16);
            ha[5] = (short)(cbuf[kk][2] >> 48);
            ha[6] = (short)((unsigned int)cbuf[kk][3] >> 16);
            ha[7] = (short)(cbuf[kk][3] >> 48);
            #pragma unroll
            for (int ct = 0; ct < 8; ++ct)
                acc[ct] = __builtin_amdgcn_mfma_f32_16x16x32_bf16(ha, wh[ct][kk], acc[ct], 0, 0, 0);
        }

        // ---- partials -> LDS (C/D: col = lane&15, row = quad*4 + r; rows 0-7 real) ----
        if (quad < 2) {
            #pragma unroll
            for (int ct = 0; ct < 8; ++ct)
                #pragma unroll
                for (int r = 0; r < 4; ++r)
                    gtile[t & 1][w][ct][quad * 4 + r][m16] = acc[ct][r];
        }
        __syncthreads();   // the ONLY barrier per step

        // ---- x loads for t+1: issued post-barrier, hidden under elementwise ----
        if (t + 1 < SEQ) xload(t + 1);

        // ---- elementwise gates; publish FIRST, then out stores ----
        if (tid < 256) {
            float gv[4];
            #pragma unroll
            for (int gg2 = 0; gg2 < 4; ++gg2) {
                const int ct = gg2 * 2 + (ec >> 4);
                const int cn = ec & 15;
                float ss = bia[gg2];
                #pragma unroll
                for (int ww = 0; ww < 8; ++ww) ss += gtile[t & 1][ww][ct][eb][cn];
                gv[gg2] = ss;
            }
            float f  = sigm(gv[0]);
            float i  = sigm(gv[1]);
            float cc = tanh_fast(gv[2]);
            float o  = sigm(gv[3]);
            c_state  = f * c_state + i * cc;
            float h_val = o * tanh_fast(c_state);
            unsigned int pword = ((unsigned int)(unsigned short)f2bf(h_val) << 16)
                               | ((unsigned int)(t + 1) & 0xFFFFu);

            unsigned int nw = __shfl_xor(pword, 1, 64);
            if (!(ec & 1)) {
                unsigned long long pk = (unsigned long long)pword
                                      | ((unsigned long long)nw << 32);
                __hip_atomic_store(
                    (unsigned long long*)(hxg + ((size_t)(t & 1) * GB + eb) * HSZ
                                              + s * 32 + ec),
                    pk, __ATOMIC_RELAXED, __HIP_MEMORY_SCOPE_AGENT);
            }

            // off-critical-path output stores (ack at local L2, drained later)
            out[((size_t)(g * GB + eb) * SEQ + t) * HSZ + s * 32 + ec] = h_val;
            if (t == SEQ - 1) {
                size_t fin = (size_t)BATCH * SEQ * HSZ;
                out[fin + (size_t)(g * GB + eb) * HSZ + s * 32 + ec] = h_val;
                out[fin + (size_t)BATCH * HSZ + (size_t)(g * GB + eb) * HSZ
                        + s * 32 + ec] = c_state;
            }
        }

        // ---- x part for t+1 from prefetched regs ----
        if (t + 1 < SEQ) xmfma();
    }
}

extern "C" void kernel_launch(void* const* d_in, const int* in_sizes, int n_in,
                              void* d_out, int out_size, void* d_ws, size_t ws_size,
                              hipStream_t stream) {
    const float* x    = (const float*)d_in[0];
    const float* W    = (const float*)d_in[1];
    const float* bias = (const float*)d_in[2];
    float* out        = (float*)d_out;

    unsigned int* hx = (unsigned int*)d_ws;

    // zero tagged exchange: epoch 0 == valid h0 = 0
    hipMemsetAsync(d_ws, 0, HEX_DW * 4, stream);

    lstm_persistent<<<256, 512, 0, stream>>>(x, W, bias, out, hx);
}

// Round 7
// 2502.796 us; speedup vs baseline: 1.4729x; 1.4729x over previous
//
#include <hip/hip_runtime.h>
#include <hip/hip_bf16.h>

// SimpleLSTM on MI355X — round 10: R8 base + pairwise fresh-poll + early xload.
//   B=64, S=512, I=512, H=1024, gates = 4H = 4096
// R9 post-mortem (REVERTED): preloading all chunks checked STALE values first
// (guaranteed fail+sleep+reload per chunk, serialized) and +32 live VGPRs;
// 2359 -> 3686us. Lesson: fresh loads must be the FIRST thing a chunk check
// sees (R8 property), and register pressure is at the cliff edge.
// R10 = R8 with exactly two changes:
//   1. PAIRWISE poll: spin on chunks {0,1} together, then {2,3}. Both chunks
//      reloaded FRESH each spin iteration; serialized far-memory round trips
//      per step drop 4 -> 2 (and pair 2's first fresh check usually passes
//      instantly since pair 1's spin covered the skew). +8 transient VGPRs.
//   2. xload(t+1) hoisted to loop TOP (before poll); xmfma stays at the end.
//      The ~900cy x HBM latency hides under poll+MFMA+elementwise instead of
//      serializing between publish and next poll.
//   Unchanged from R8: agent-scope relaxed atomics, epoch-in-data tags,
//   8 groups x 32 CUs x 8 batches, wh/wx0 register-resident, wxl/gtile LDS
//   layout (96KB), two barriers, publish-after-barrier2, launch_bounds(512,2).

#define BATCH 64
#define SEQ   512
#define ISZ   512
#define HSZ   1024
#define G4    4096

#define NGRP  8
#define GB    8      // batches per group
#define SLOTS 32     // CUs per group

typedef short bf16x8 __attribute__((ext_vector_type(8)));
typedef float f32x4  __attribute__((ext_vector_type(4)));

#define HEX_DW (NGRP * 2 * GB * HSZ)   // 131072 tagged dwords = 512 KB

static __device__ __forceinline__ short f2bf(float f) {
    __hip_bfloat16 h = __float2bfloat16(f);
    return *reinterpret_cast<short*>(&h);
}
static __device__ __forceinline__ float sigm(float x) {
    return 1.f / (1.f + __expf(-x));
}
static __device__ __forceinline__ float tanh_fast(float x) {
    x = fminf(15.f, fmaxf(-15.f, x));
    float e = __expf(2.f * x);
    return (e - 1.f) / (e + 1.f);
}

__global__ __launch_bounds__(512, 2) void lstm_persistent(
    const float* __restrict__ x,     // [B][S][I] fp32
    const float* __restrict__ W,     // [I+H][4H] fp32
    const float* __restrict__ bias,  // [4H] fp32
    float* __restrict__ out,         // [B][S][H], then [B][H] h, [B][H] c
    unsigned int* __restrict__ hx)   // [NGRP][2][GB][HSZ] tagged words
{
    const int tid  = threadIdx.x;
    const int bid  = blockIdx.x;
    const int g    = bid & 7;           // group
    const int s    = bid >> 3;          // slot 0..31: owns h-cols [32s, 32s+32)
    const int w    = tid >> 6;          // wave 0..7 = h-K slice [128w, +128)
    const int lane = tid & 63;
    const int m16  = lane & 15;
    const int quad = lane >> 4;

    __shared__ short wxl[8][8][64][8];      // Wx kk=1 frags, 64 KB (self-wave read)
    __shared__ float gtile[8][8][8][16];    // 8 waves x 8 col-tiles x 8 rows, 32 KB

    // ---- preload weights as MFMA B-fragments ----
    // slot s: 8 col-tiles ct -> col = (ct>>1)*1024 + s*32 + (ct&1)*16
    // B-frag (16x16x32): lane holds B[k = quad*8 + j][n = lane&15]
    bf16x8 wh[8][4];
    bf16x8 wx0[8];
    #pragma unroll
    for (int ct = 0; ct < 8; ++ct) {
        const int col = (ct >> 1) * 1024 + s * 32 + (ct & 1) * 16 + m16;
        #pragma unroll
        for (int kk = 0; kk < 4; ++kk)
            #pragma unroll
            for (int j = 0; j < 8; ++j)
                wh[ct][kk][j] = f2bf(W[(size_t)(ISZ + w * 128 + kk * 32 + quad * 8 + j) * G4 + col]);
        bf16x8 t0, t1;
        #pragma unroll
        for (int j = 0; j < 8; ++j) {
            t0[j] = f2bf(W[(size_t)(w * 64 + quad * 8 + j) * G4 + col]);
            t1[j] = f2bf(W[(size_t)(w * 64 + 32 + quad * 8 + j) * G4 + col]);
        }
        wx0[ct] = t0;
        *(bf16x8*)&wxl[w][ct][lane][0] = t1;
    }

    // elementwise mapping (tid < 256): eb = batch-in-group, ec = h-col-in-32
    const int eb = tid >> 5;
    const int ec = tid & 31;
    float bia[4] = {0.f, 0.f, 0.f, 0.f};
    if (tid < 256) {
        #pragma unroll
        for (int gg2 = 0; gg2 < 4; ++gg2) bia[gg2] = bias[gg2 * 1024 + s * 32 + ec];
    }
    float c_state = 0.f;

    unsigned int* hxg = hx + (size_t)g * (2 * GB * HSZ);

    f32x4 acc[8];
    f32x4 xr0 = {0,0,0,0}, xr1 = {0,0,0,0}, xr2 = {0,0,0,0}, xr3 = {0,0,0,0};

    // issue x loads for step tt (this wave's x-K slice [64w, +64))
    auto xload = [&](int tt) {
        if (m16 < 8) {
            const float* xr = x + ((size_t)(g * GB + m16) * SEQ + tt) * ISZ
                                + w * 64 + quad * 8;
            xr0 = *(const f32x4*)xr;
            xr1 = *(const f32x4*)(xr + 4);
            xr2 = *(const f32x4*)(xr + 32);
            xr3 = *(const f32x4*)(xr + 36);
        }
    };
    // acc = x @ Wx from the prefetched registers (resets acc)
    auto xmfma = [&]() {
        #pragma unroll
        for (int ct = 0; ct < 8; ++ct) acc[ct] = (f32x4){0.f, 0.f, 0.f, 0.f};
        bf16x8 a0, a1;
        a0[0]=f2bf(xr0[0]); a0[1]=f2bf(xr0[1]); a0[2]=f2bf(xr0[2]); a0[3]=f2bf(xr0[3]);
        a0[4]=f2bf(xr1[0]); a0[5]=f2bf(xr1[1]); a0[6]=f2bf(xr1[2]); a0[7]=f2bf(xr1[3]);
        a1[0]=f2bf(xr2[0]); a1[1]=f2bf(xr2[1]); a1[2]=f2bf(xr2[2]); a1[3]=f2bf(xr2[3]);
        a1[4]=f2bf(xr3[0]); a1[5]=f2bf(xr3[1]); a1[6]=f2bf(xr3[2]); a1[7]=f2bf(xr3[3]);
        #pragma unroll
        for (int ct = 0; ct < 8; ++ct)
            acc[ct] = __builtin_amdgcn_mfma_f32_16x16x32_bf16(a0, wx0[ct], acc[ct], 0, 0, 0);
        #pragma unroll
        for (int ct = 0; ct < 8; ++ct) {
            bf16x8 bx = *(const bf16x8*)&wxl[w][ct][lane][0];
            acc[ct] = __builtin_amdgcn_mfma_f32_16x16x32_bf16(a1, bx, acc[ct], 0, 0, 0);
        }
    };

    __syncthreads();   // wxl staged
    xload(0);
    xmfma();           // acc holds x-part of t=0

    for (int t = 0; t < SEQ; ++t) {
        // ---- issue x loads for t+1 FIRST: latency hides under poll+compute ----
        if (t + 1 < SEQ) xload(t + 1);

        // ---- pairwise poll + h-MFMA (fresh loads every spin iteration) ----
        // tag target = t (t=0 passes immediately: memset zeros == epoch 0, h=0)
        const unsigned int tg = (unsigned int)t & 0xFFFFu;
        const int rb = (t + 1) & 1;
        const unsigned long long* hp64 = (const unsigned long long*)
            (hxg + ((size_t)rb * GB + m16) * HSZ + w * 128 + quad * 8);

        #pragma unroll
        for (int pr = 0; pr < 2; ++pr) {
            unsigned long long cb[2][4];
            #pragma unroll
            for (int c = 0; c < 2; ++c)
                #pragma unroll
                for (int j = 0; j < 4; ++j) cb[c][j] = 0ull;

            long long guard = 0;
            for (;;) {
                int ok = 1;
                if (m16 < 8) {
                    // fresh loads of BOTH chunks of this pair, issued together
                    #pragma unroll
                    for (int c = 0; c < 2; ++c)
                        #pragma unroll
                        for (int j = 0; j < 4; ++j)
                            cb[c][j] = __hip_atomic_load(
                                hp64 + (size_t)(pr * 2 + c) * 16 + j,
                                __ATOMIC_RELAXED, __HIP_MEMORY_SCOPE_AGENT);
                    unsigned int bad = 0;
                    #pragma unroll
                    for (int c = 0; c < 2; ++c)
                        #pragma unroll
                        for (int j = 0; j < 4; ++j)
                            bad |= ((unsigned int)cb[c][j] ^ tg)
                                 | ((unsigned int)(cb[c][j] >> 32) ^ tg);
                    ok = ((bad & 0xFFFFu) == 0u);
                }
                if (__all(ok)) break;
                __builtin_amdgcn_s_sleep(1);
                if (++guard > (1LL << 22)) break;   // safety valve (never trips)
            }

            #pragma unroll
            for (int c = 0; c < 2; ++c) {
                const int kk = pr * 2 + c;
                bf16x8 ha;
                ha[0] = (short)((unsigned int)cb[c][0] >> 16);
                ha[1] = (short)(cb[c][0] >> 48);
                ha[2] = (short)((unsigned int)cb[c][1] >> 16);
                ha[3] = (short)(cb[c][1] >> 48);
                ha[4] = (short)((unsigned int)cb[c][2] >> 16);
                ha[5] = (short)(cb[c][2] >> 48);
                ha[6] = (short)((unsigned int)cb[c][3] >> 16);
                ha[7] = (short)(cb[c][3] >> 48);
                #pragma unroll
                for (int ct = 0; ct < 8; ++ct)
                    acc[ct] = __builtin_amdgcn_mfma_f32_16x16x32_bf16(ha, wh[ct][kk], acc[ct], 0, 0, 0);
            }
        }

        // ---- partials -> LDS (C/D: col = lane&15, row = quad*4 + r; rows 0-7 real) ----
        if (quad < 2) {
            #pragma unroll
            for (int ct = 0; ct < 8; ++ct)
                #pragma unroll
                for (int r = 0; r < 4; ++r)
                    gtile[w][ct][quad * 4 + r][m16] = acc[ct][r];
        }
        __syncthreads();

        // ---- elementwise gates (registers only after this) ----
        float h_val = 0.f;
        unsigned int pword = 0;
        if (tid < 256) {
            float gv[4];
            #pragma unroll
            for (int gg2 = 0; gg2 < 4; ++gg2) {
                const int ct = gg2 * 2 + (ec >> 4);
                const int cn = ec & 15;
                float ss = bia[gg2];
                #pragma unroll
                for (int ww = 0; ww < 8; ++ww) ss += gtile[ww][ct][eb][cn];
                gv[gg2] = ss;
            }
            float f  = sigm(gv[0]);
            float i  = sigm(gv[1]);
            float cc = tanh_fast(gv[2]);
            float o  = sigm(gv[3]);
            c_state  = f * c_state + i * cc;
            h_val    = o * tanh_fast(c_state);
            pword = ((unsigned int)(unsigned short)f2bf(h_val) << 16)
                  | ((unsigned int)(t + 1) & 0xFFFFu);
        }
        __syncthreads();   // protects gtile reuse; cheap (no pending vmem deps)

        // ---- publish: 64-bit agent-scope store of two tagged words ----
        if (tid < 256) {
            unsigned int nw = __shfl_xor(pword, 1, 64);
            if (!(ec & 1)) {
                unsigned long long pk = (unsigned long long)pword
                                      | ((unsigned long long)nw << 32);
                __hip_atomic_store(
                    (unsigned long long*)(hxg + ((size_t)(t & 1) * GB + eb) * HSZ
                                              + s * 32 + ec),
                    pk, __ATOMIC_RELAXED, __HIP_MEMORY_SCOPE_AGENT);
            }
            // off-critical-path output stores
            out[((size_t)(g * GB + eb) * SEQ + t) * HSZ + s * 32 + ec] = h_val;
            if (t == SEQ - 1) {
                size_t fin = (size_t)BATCH * SEQ * HSZ;
                out[fin + (size_t)(g * GB + eb) * HSZ + s * 32 + ec] = h_val;
                out[fin + (size_t)BATCH * HSZ + (size_t)(g * GB + eb) * HSZ
                        + s * 32 + ec] = c_state;
            }
        }

        // ---- x part for t+1 from prefetched regs (loads long since landed) ----
        if (t + 1 < SEQ) xmfma();
    }
}

extern "C" void kernel_launch(void* const* d_in, const int* in_sizes, int n_in,
                              void* d_out, int out_size, void* d_ws, size_t ws_size,
                              hipStream_t stream) {
    const float* x    = (const float*)d_in[0];
    const float* W    = (const float*)d_in[1];
    const float* bias = (const float*)d_in[2];
    float* out        = (float*)d_out;

    unsigned int* hx = (unsigned int*)d_ws;

    // zero tagged exchange: epoch 0 == valid h0 = 0
    hipMemsetAsync(d_ws, 0, HEX_DW * 4, stream);

    lstm_persistent<<<256, 512, 0, stream>>>(x, W, bias, out, hx);
}